// Round 5
// baseline (40001.718 us; speedup 1.0000x reference)
//
#include <hip/hip_runtime.h>
#include <stdint.h>

// TinyRNN: 2-layer tanh RNN. B=64, T=2048, I=H=512.
// Persistent grid, 32 blocks (16 A + 16 B), STRICT lockstep flag barrier per iter.
// Iter k: A computes h0(k) = tanh(x(k)@Wih0 + h0(k-1)@Whh0 + b0)  [x-half
// precomputed in prev iter's barrier window]; B computes h1(k-1).
// PRECISION: the recurrence has knife-edge batches (steep bistable map, per-step
// error gain ~25). Plain bf16 state/weights FAILED (absmax 7e-2 > 2e-2).
// Fix: hi+lo bf16 split for h, x, W; each matmul = 3 MFMA passes
// (hi@Whi + lo@Whi + hi@Wlo) -> ~f32-matmul parity (~1e-4 preact error).

#define BDIM 64
#define TDIM 2048
#define IDIM 512
#define HDIM 512

#define NBLK 32
#define NA   16
#define CPB  32          // output cols per block (2 MFMA col-tiles)
#define BH   (BDIM * HDIM)   // 32768 elems

typedef float f32x4 __attribute__((ext_vector_type(4)));
typedef __bf16 bf16x8 __attribute__((ext_vector_type(8)));

__device__ __forceinline__ float fast_tanh(float z) {
    // tanh(z) = 1 - 2/(exp(2z)+1); ~1e-7 abs err; exact +-1 saturation
    float e = __expf(2.0f * z);
    return 1.0f - 2.0f / (e + 1.0f);
}

__global__ __launch_bounds__(256, 1) void rnn_persistent(
    const float* __restrict__ x,
    const float* __restrict__ wih0, const float* __restrict__ whh0,
    const float* __restrict__ bih0, const float* __restrict__ bhh0,
    const float* __restrict__ wih1, const float* __restrict__ whh1,
    const float* __restrict__ bih1, const float* __restrict__ bhh1,
    float* __restrict__ out, unsigned char* __restrict__ ws) {

    unsigned* flags = (unsigned*)ws;                       // [32] monotone iter counters
    // h state: per slot 2*BH bf16 elems: [0,BH)=hi, [BH,2BH)=lo. 2 slots per layer.
    __bf16* h0base = (__bf16*)(ws + 256);                  // 2 slots x 2*BH
    __bf16* h1base = (__bf16*)(ws + 256 + 2 * (2 * BH) * 2);  // bytes: 2 slots x 4*BH

    const int blk  = blockIdx.x;
    const bool isA = (blk < NA);
    const int c0   = (isA ? blk : blk - NA) * CPB;
    const int tx   = threadIdx.x;
    const int lane = tx & 63;
    const int wv   = tx >> 6;
    const int r0   = wv * 16;                  // this wave's 16 batch rows

    // ---- one-time: stage weight slice to LDS (hi+lo) in MFMA B-fragment order ----
    // entry (kk,t,lane) = W[kk*32 + (lane>>4)*8 + j][c0 + t*16 + (lane&15)], j=0..7
    __shared__ __bf16 WH[4096 * 8];   // 64 KB  (bf16 hi)
    __shared__ __bf16 WL[4096 * 8];   // 64 KB  (bf16 lo residual)
    {
        const float* W1 = isA ? wih0 : wih1;   // K rows   0..511  (input half)
        const float* W2 = isA ? whh0 : whh1;   // K rows 512..1023 (recurrent half)
        for (int e = tx; e < 4096; e += 256) {
            int kk = e >> 7, t = (e >> 6) & 1, l = e & 63;
            int kbase = kk * 32 + ((l >> 4) << 3);
            int col = c0 + t * 16 + (l & 15);
            bf16x8 vh, vl;
#pragma unroll
            for (int j = 0; j < 8; ++j) {
                int kidx = kbase + j;
                float w = (kidx < 512) ? W1[(size_t)kidx * HDIM + col]
                                       : W2[(size_t)(kidx - 512) * HDIM + col];
                __bf16 hi = (__bf16)w;
                vh[j] = hi;
                vl[j] = (__bf16)(w - (float)hi);
            }
            *reinterpret_cast<bf16x8*>(&WH[e * 8]) = vh;
            *reinterpret_cast<bf16x8*>(&WL[e * 8]) = vl;
        }
    }
    const int colD = c0 + (lane & 15);         // C/D: col = lane&15 (+16 for tile 1)
    const int rowD = r0 + ((lane >> 4) << 2);  // C/D: rows rowD..rowD+3
    const int rA   = r0 + (lane & 15);         // A-frag: row = lane&15
    const int kfo  = (lane >> 4) << 3;         // A-frag: k-offset in 32-wide window
    const float bias0 = isA ? (bih0[colD] + bhh0[colD]) : (bih1[colD] + bhh1[colD]);
    const float bias1 = isA ? (bih0[colD + 16] + bhh0[colD + 16])
                            : (bih1[colD + 16] + bhh1[colD + 16]);
    __syncthreads();

    // 3-pass x-half: split x into hi+lo on the fly; hi@Whi + lo@Whi + hi@Wlo
    auto xhalf_mfma = [&](const float* xrow, f32x4& a0, f32x4& a1) {
#pragma unroll
        for (int kk = 0; kk < 16; ++kk) {
            f32x4 l4 = *reinterpret_cast<const f32x4*>(xrow + kk * 32 + kfo);
            f32x4 h4 = *reinterpret_cast<const f32x4*>(xrow + kk * 32 + kfo + 4);
            bf16x8 xh, xl;
#pragma unroll
            for (int j = 0; j < 4; ++j) {
                __bf16 a = (__bf16)l4[j]; xh[j] = a;     xl[j] = (__bf16)(l4[j] - (float)a);
                __bf16 b = (__bf16)h4[j]; xh[4 + j] = b; xl[4 + j] = (__bf16)(h4[j] - (float)b);
            }
            bf16x8 w0h = *reinterpret_cast<const bf16x8*>(&WH[((kk * 2 + 0) * 64 + lane) * 8]);
            bf16x8 w1h = *reinterpret_cast<const bf16x8*>(&WH[((kk * 2 + 1) * 64 + lane) * 8]);
            bf16x8 w0l = *reinterpret_cast<const bf16x8*>(&WL[((kk * 2 + 0) * 64 + lane) * 8]);
            bf16x8 w1l = *reinterpret_cast<const bf16x8*>(&WL[((kk * 2 + 1) * 64 + lane) * 8]);
            a0 = __builtin_amdgcn_mfma_f32_16x16x32_bf16(xh, w0h, a0, 0, 0, 0);
            a1 = __builtin_amdgcn_mfma_f32_16x16x32_bf16(xh, w1h, a1, 0, 0, 0);
            a0 = __builtin_amdgcn_mfma_f32_16x16x32_bf16(xl, w0h, a0, 0, 0, 0);
            a1 = __builtin_amdgcn_mfma_f32_16x16x32_bf16(xl, w1h, a1, 0, 0, 0);
            a0 = __builtin_amdgcn_mfma_f32_16x16x32_bf16(xh, w0l, a0, 0, 0, 0);
            a1 = __builtin_amdgcn_mfma_f32_16x16x32_bf16(xh, w1l, a1, 0, 0, 0);
        }
    };

    // 3-pass h-half from hi/lo state rows; weight k-window base = koff (0 or 16)
    auto hhalf_mfma = [&](const __bf16* hi_row, const __bf16* lo_row, int koff,
                          f32x4& a0, f32x4& a1) {
#pragma unroll
        for (int kk = 0; kk < 16; ++kk) {
            bf16x8 hh = *reinterpret_cast<const bf16x8*>(hi_row + kk * 32 + kfo);
            bf16x8 w0h = *reinterpret_cast<const bf16x8*>(&WH[(((koff + kk) * 2 + 0) * 64 + lane) * 8]);
            bf16x8 w1h = *reinterpret_cast<const bf16x8*>(&WH[(((koff + kk) * 2 + 1) * 64 + lane) * 8]);
            bf16x8 w0l = *reinterpret_cast<const bf16x8*>(&WL[(((koff + kk) * 2 + 0) * 64 + lane) * 8]);
            bf16x8 w1l = *reinterpret_cast<const bf16x8*>(&WL[(((koff + kk) * 2 + 1) * 64 + lane) * 8]);
            a0 = __builtin_amdgcn_mfma_f32_16x16x32_bf16(hh, w0h, a0, 0, 0, 0);
            a1 = __builtin_amdgcn_mfma_f32_16x16x32_bf16(hh, w1h, a1, 0, 0, 0);
            a0 = __builtin_amdgcn_mfma_f32_16x16x32_bf16(hh, w0l, a0, 0, 0, 0);
            a1 = __builtin_amdgcn_mfma_f32_16x16x32_bf16(hh, w1l, a1, 0, 0, 0);
        }
#pragma unroll
        for (int kk = 0; kk < 16; ++kk) {
            bf16x8 hl = *reinterpret_cast<const bf16x8*>(lo_row + kk * 32 + kfo);
            bf16x8 w0h = *reinterpret_cast<const bf16x8*>(&WH[(((koff + kk) * 2 + 0) * 64 + lane) * 8]);
            bf16x8 w1h = *reinterpret_cast<const bf16x8*>(&WH[(((koff + kk) * 2 + 1) * 64 + lane) * 8]);
            a0 = __builtin_amdgcn_mfma_f32_16x16x32_bf16(hl, w0h, a0, 0, 0, 0);
            a1 = __builtin_amdgcn_mfma_f32_16x16x32_bf16(hl, w1h, a1, 0, 0, 0);
        }
    };

    // ---- prologue (A): acc_x(0) = x(0)@Wih0 (hi/lo, 3 passes) ----
    f32x4 accx0 = {0.f, 0.f, 0.f, 0.f}, accx1 = {0.f, 0.f, 0.f, 0.f};
    if (isA) xhalf_mfma(x + (size_t)rA * TDIM * IDIM, accx0, accx1);

    float vout[2][4];   // B: carried from compute phase to window out-stores

    for (int k = 0; k <= TDIM; ++k) {
        // ================= critical compute phase =================
        if (isA && k < TDIM) {
            const __bf16* hs = h0base + ((k + 1) & 1) * (2 * BH);    // h0(k-1) slot
            f32x4 acc0 = accx0, acc1 = accx1;
            hhalf_mfma(hs + rA * HDIM, hs + BH + rA * HDIM, 16, acc0, acc1);
            __bf16* hd = h0base + (k & 1) * (2 * BH);                // h0(k) slot
#pragma unroll
            for (int m = 0; m < 4; ++m) {
                float v0 = fast_tanh(acc0[m] + bias0);
                float v1 = fast_tanh(acc1[m] + bias1);
                __bf16 h0v = (__bf16)v0, h1v = (__bf16)v1;
                hd[(rowD + m) * HDIM + colD] = h0v;                  // hi (precede flag)
                hd[(rowD + m) * HDIM + colD + 16] = h1v;
                hd[BH + (rowD + m) * HDIM + colD] = (__bf16)(v0 - (float)h0v);  // lo
                hd[BH + (rowD + m) * HDIM + colD + 16] = (__bf16)(v1 - (float)h1v);
                if (k == TDIM - 1) {   // final_h layer 0
                    out[(size_t)BDIM * TDIM * HDIM + (size_t)(rowD + m) * HDIM + colD] = v0;
                    out[(size_t)BDIM * TDIM * HDIM + (size_t)(rowD + m) * HDIM + colD + 16] = v1;
                }
            }
        } else if (!isA && k >= 1) {
            // h1(k-1) = tanh(h0(k-1)@Wih1 + h1(k-2)@Whh1 + b1)
            const __bf16* s0 = h0base + ((k + 1) & 1) * (2 * BH);    // h0(k-1)
            const __bf16* s1 = h1base + (k & 1) * (2 * BH);          // h1(k-2)
            f32x4 acc0 = {0.f, 0.f, 0.f, 0.f}, acc1 = {0.f, 0.f, 0.f, 0.f};
            hhalf_mfma(s1 + rA * HDIM, s1 + BH + rA * HDIM, 16, acc0, acc1);  // @Whh1
            hhalf_mfma(s0 + rA * HDIM, s0 + BH + rA * HDIM, 0, acc0, acc1);   // @Wih1
            __bf16* hd = h1base + ((k + 1) & 1) * (2 * BH);          // h1(k-1) slot
#pragma unroll
            for (int m = 0; m < 4; ++m) {
                vout[0][m] = fast_tanh(acc0[m] + bias0);
                vout[1][m] = fast_tanh(acc1[m] + bias1);
                if (k < TDIM) {
                    __bf16 a = (__bf16)vout[0][m], b = (__bf16)vout[1][m];
                    hd[(rowD + m) * HDIM + colD] = a;
                    hd[(rowD + m) * HDIM + colD + 16] = b;
                    hd[BH + (rowD + m) * HDIM + colD] = (__bf16)(vout[0][m] - (float)a);
                    hd[BH + (rowD + m) * HDIM + colD + 16] = (__bf16)(vout[1][m] - (float)b);
                }
            }
            if (k == TDIM) {  // last iter: no barrier follows — store outputs inline
                const int t = k - 1;
#pragma unroll
                for (int m = 0; m < 4; ++m) {
                    __builtin_nontemporal_store(vout[0][m],
                        &out[((size_t)(rowD + m) * TDIM + t) * HDIM + colD]);
                    __builtin_nontemporal_store(vout[1][m],
                        &out[((size_t)(rowD + m) * TDIM + t) * HDIM + colD + 16]);
                    out[(size_t)BDIM * TDIM * HDIM + (size_t)(BDIM + rowD + m) * HDIM + colD] = vout[0][m];
                    out[(size_t)BDIM * TDIM * HDIM + (size_t)(BDIM + rowD + m) * HDIM + colD + 16] = vout[1][m];
                }
            }
        }

        // ================= arrive =================
        if (k < TDIM) {
            __syncthreads();                   // all block stores issued (vmcnt drained)
            if (tx == 0) {
                __threadfence();               // write back dirty L2 (cross-XCD publish)
                __hip_atomic_store(&flags[blk], (unsigned)(k + 1),
                                   __ATOMIC_RELEASE, __HIP_MEMORY_SCOPE_AGENT);
            }
        }

        // ======== barrier window: off-critical-path work ========
        if (isA) {
            if (k + 1 < TDIM) {    // x(k+1) 3-pass x-half for next iter
                f32x4 a0 = {0.f, 0.f, 0.f, 0.f}, a1 = {0.f, 0.f, 0.f, 0.f};
                xhalf_mfma(x + ((size_t)rA * TDIM + (k + 1)) * IDIM, a0, a1);
                accx0 = a0; accx1 = a1;
            }
        } else if (k >= 1 && k < TDIM) {
            const int t = k - 1;   // streaming output[b, t, :]
#pragma unroll
            for (int m = 0; m < 4; ++m) {
                __builtin_nontemporal_store(vout[0][m],
                    &out[((size_t)(rowD + m) * TDIM + t) * HDIM + colD]);
                __builtin_nontemporal_store(vout[1][m],
                    &out[((size_t)(rowD + m) * TDIM + t) * HDIM + colD + 16]);
            }
        }

        // ================= wait (strict lockstep: all >= k+1) =================
        if (k < TDIM) {
            if (wv == 0) {
                const unsigned tgt = (unsigned)(k + 1);
                while (true) {
                    unsigned f = __hip_atomic_load(&flags[lane & (NBLK - 1)], __ATOMIC_ACQUIRE,
                                                   __HIP_MEMORY_SCOPE_AGENT);
                    if (__all((int)(f >= tgt))) break;
                    __builtin_amdgcn_s_sleep(1);
                }
            }
            __syncthreads();
            __threadfence();   // every wave invalidates L1/L2 before reading fresh h
        }
    }
}

extern "C" void kernel_launch(void* const* d_in, const int* in_sizes, int n_in,
                              void* d_out, int out_size, void* d_ws, size_t ws_size,
                              hipStream_t stream) {
    (void)in_sizes; (void)n_in; (void)out_size; (void)ws_size;
    const float* x    = (const float*)d_in[0];
    const float* wih0 = (const float*)d_in[1];
    const float* whh0 = (const float*)d_in[2];
    const float* bih0 = (const float*)d_in[3];
    const float* bhh0 = (const float*)d_in[4];
    const float* wih1 = (const float*)d_in[5];
    const float* whh1 = (const float*)d_in[6];
    const float* bih1 = (const float*)d_in[7];
    const float* bhh1 = (const float*)d_in[8];
    float* out = (float*)d_out;
    unsigned char* ws = (unsigned char*)d_ws;

    // zero flags + h0/h1 hi+lo double buffers (h(-1)=0); d_ws is 0xAA otherwise
    // bytes: 256 + (h0: 2 slots * 4*BH) + (h1: 2 slots * 4*BH) = 256 + 524288
    hipMemsetAsync(ws, 0, 256 + 4 * (size_t)(2 * BDIM * HDIM * 2), stream);

    void* args[] = {&x, &wih0, &whh0, &bih0, &bhh0, &wih1, &whh1, &bih1, &bhh1, &out, &ws};
    hipError_t err = hipLaunchCooperativeKernel((void*)rnn_persistent, dim3(NBLK),
                                                dim3(256), args, 0, stream);
    if (err != hipSuccess) {
        // fallback: plain launch — 32 blocks <= 256 CUs, trivially co-resident
        rnn_persistent<<<dim3(NBLK), dim3(256), 0, stream>>>(
            x, wih0, whh0, bih0, bhh0, wih1, whh1, bih1, bhh1, out, ws);
    }
}

// Round 7
// 27038.727 us; speedup vs baseline: 1.4794x; 1.4794x over previous
//
#include <hip/hip_runtime.h>
#include <stdint.h>

// TinyRNN: 2-layer tanh RNN. B=64, T=2048, I=H=512.
// Phase 1: bulk GEMM preact0 = x @ Wih0 (hi/lo bf16 3-pass, f32-parity), all
//          timesteps in parallel, stored f32 into d_out (slot [b,t,:] holds
//          preact0(t) until consumed; B overwrites it with h1(t) at iter t+1;
//          ordering guaranteed by the flag dependencies — 2 barriers apart).
// Phase 2: persistent grid, 32 blocks (16 A + 16 B), per-iter flag sync.
//   A at iter k: h0(k) = tanh(preact0(k) + h0(k-1)@Whh0 + b0)
//   B at iter k: h1(k-1) = tanh(h0(k-1)@Wih1 + h1(k-2)@Whh1 + b1)
//   Deps: A waits {A>=k+1, B>=k-2} (4-slot h0 ring); B waits {all>=k+1}.
// PRECISION: knife-edge batches give per-step error gain ~25; plain bf16
// failed (7e-2). hi+lo bf16 split of h/x/W with 3 MFMA passes passed (3.9e-3).
// SYNC: relaxed spin (no L2 inv per poll) + single acquire fence; release
// store publishes (round-5's 19.5us/iter was redundant x-fetch [3.15 GB
// FETCH = 16x128KB/iter, measured] + per-wave threadfence cache maintenance).

#define BDIM 64
#define TDIM 2048
#define IDIM 512
#define HDIM 512

#define NBLK 32
#define NA   16
#define CPB  32              // output cols per block (2 MFMA col-tiles)
#define BH   (BDIM * HDIM)   // 32768 elems

typedef float f32x4 __attribute__((ext_vector_type(4)));
typedef __bf16 bf16x8 __attribute__((ext_vector_type(8)));

__device__ __forceinline__ float fast_tanh(float z) {
    float e = __expf(2.0f * z);
    return 1.0f - 2.0f / (e + 1.0f);
}

// ======================= Phase 1: preact0 = x @ Wih0 =======================
// grid = (131072/256) * (512/32) = 512*16 = 8192 blocks, 256 thr.
__global__ __launch_bounds__(256, 2) void xw0_gemm(
    const float* __restrict__ x, const float* __restrict__ wih0,
    float* __restrict__ pre) {
    const int nt = blockIdx.x & 15;
    const int mt = blockIdx.x >> 4;
    const int c0 = nt * 32;
    const int tx = threadIdx.x, lane = tx & 63, wv = tx >> 6;

    __shared__ __bf16 WH[16 * 2 * 64 * 8];   // 32 KB
    __shared__ __bf16 WL[16 * 2 * 64 * 8];   // 32 KB
    for (int e = tx; e < 16 * 2 * 64; e += 256) {
        int kk = e >> 7, t = (e >> 6) & 1, l = e & 63;
        int kbase = kk * 32 + ((l >> 4) << 3);
        int col = c0 + t * 16 + (l & 15);
        bf16x8 vh, vl;
#pragma unroll
        for (int j = 0; j < 8; ++j) {
            float w = wih0[(size_t)(kbase + j) * HDIM + col];
            __bf16 hi = (__bf16)w;
            vh[j] = hi; vl[j] = (__bf16)(w - (float)hi);
        }
        *reinterpret_cast<bf16x8*>(&WH[e * 8]) = vh;
        *reinterpret_cast<bf16x8*>(&WL[e * 8]) = vl;
    }
    __syncthreads();

    const int kfo = (lane >> 4) << 3;
    const int rbase = mt * 256 + wv * 64;      // wave's 64 rows (row = b*T + t)
    const int rA = lane & 15;
    f32x4 acc[4][2];
#pragma unroll
    for (int rt = 0; rt < 4; ++rt) {
        acc[rt][0] = {0.f, 0.f, 0.f, 0.f};
        acc[rt][1] = {0.f, 0.f, 0.f, 0.f};
    }
#pragma unroll 2
    for (int kk = 0; kk < 16; ++kk) {
        bf16x8 w0h = *reinterpret_cast<const bf16x8*>(&WH[((kk * 2 + 0) * 64 + lane) * 8]);
        bf16x8 w1h = *reinterpret_cast<const bf16x8*>(&WH[((kk * 2 + 1) * 64 + lane) * 8]);
        bf16x8 w0l = *reinterpret_cast<const bf16x8*>(&WL[((kk * 2 + 0) * 64 + lane) * 8]);
        bf16x8 w1l = *reinterpret_cast<const bf16x8*>(&WL[((kk * 2 + 1) * 64 + lane) * 8]);
#pragma unroll
        for (int rt = 0; rt < 4; ++rt) {
            const float* xr = x + (size_t)(rbase + rt * 16 + rA) * IDIM + kk * 32 + kfo;
            f32x4 l4 = *reinterpret_cast<const f32x4*>(xr);
            f32x4 h4 = *reinterpret_cast<const f32x4*>(xr + 4);
            bf16x8 xh, xl;
#pragma unroll
            for (int j = 0; j < 4; ++j) {
                __bf16 a = (__bf16)l4[j]; xh[j] = a;     xl[j] = (__bf16)(l4[j] - (float)a);
                __bf16 b = (__bf16)h4[j]; xh[4 + j] = b; xl[4 + j] = (__bf16)(h4[j] - (float)b);
            }
            acc[rt][0] = __builtin_amdgcn_mfma_f32_16x16x32_bf16(xh, w0h, acc[rt][0], 0, 0, 0);
            acc[rt][1] = __builtin_amdgcn_mfma_f32_16x16x32_bf16(xh, w1h, acc[rt][1], 0, 0, 0);
            acc[rt][0] = __builtin_amdgcn_mfma_f32_16x16x32_bf16(xl, w0h, acc[rt][0], 0, 0, 0);
            acc[rt][1] = __builtin_amdgcn_mfma_f32_16x16x32_bf16(xl, w1h, acc[rt][1], 0, 0, 0);
            acc[rt][0] = __builtin_amdgcn_mfma_f32_16x16x32_bf16(xh, w0l, acc[rt][0], 0, 0, 0);
            acc[rt][1] = __builtin_amdgcn_mfma_f32_16x16x32_bf16(xh, w1l, acc[rt][1], 0, 0, 0);
        }
    }
    const int rowOff = (lane >> 4) << 2, colL = lane & 15;
#pragma unroll
    for (int rt = 0; rt < 4; ++rt)
#pragma unroll
        for (int ct = 0; ct < 2; ++ct)
#pragma unroll
            for (int m = 0; m < 4; ++m)
                __builtin_nontemporal_store(acc[rt][ct][m],
                    &pre[(size_t)(rbase + rt * 16 + rowOff + m) * HDIM + c0 + ct * 16 + colL]);
}

// ======================= Phase 2: persistent recurrence =======================
__global__ __launch_bounds__(256, 1) void rnn_persistent(
    const float* __restrict__ whh0,
    const float* __restrict__ bih0, const float* __restrict__ bhh0,
    const float* __restrict__ wih1, const float* __restrict__ whh1,
    const float* __restrict__ bih1, const float* __restrict__ bhh1,
    float* out, unsigned char* __restrict__ ws) {

    unsigned* flags = (unsigned*)ws;                    // flag i at flags[i*32] (128-B apart)
    __bf16* h0base  = (__bf16*)(ws + 4096);             // 4 slots x (2*BH): [hi|lo]
    __bf16* h1base  = (__bf16*)(ws + 4096 + 4 * (size_t)(2 * BH) * 2);  // 2 slots

    const int blk  = blockIdx.x;
    const bool isA = (blk < NA);
    const int c0   = (isA ? blk : blk - NA) * CPB;
    const int tx   = threadIdx.x;
    const int lane = tx & 63;
    const int wv   = tx >> 6;
    const int r0   = wv * 16;

    // A stages Whh0 only (kk 0..15); B stages Wih1 (kk 0..15) + Whh1 (kk 16..31).
    __shared__ __bf16 WH[32 * 2 * 64 * 8];  // 64 KB
    __shared__ __bf16 WL[32 * 2 * 64 * 8];  // 64 KB
    {
        const int ne = (isA ? 16 : 32) * 2 * 64;
        const float* W1 = isA ? whh0 : wih1;
        for (int e = tx; e < ne; e += 256) {
            int kk = e >> 7, t = (e >> 6) & 1, l = e & 63;
            int kbase = kk * 32 + ((l >> 4) << 3);
            int col = c0 + t * 16 + (l & 15);
            bf16x8 vh, vl;
#pragma unroll
            for (int j = 0; j < 8; ++j) {
                int kidx = kbase + j;
                float w = (kidx < 512) ? W1[(size_t)kidx * HDIM + col]
                                       : whh1[(size_t)(kidx - 512) * HDIM + col];
                __bf16 hi = (__bf16)w;
                vh[j] = hi; vl[j] = (__bf16)(w - (float)hi);
            }
            *reinterpret_cast<bf16x8*>(&WH[e * 8]) = vh;
            *reinterpret_cast<bf16x8*>(&WL[e * 8]) = vl;
        }
    }
    const int colD = c0 + (lane & 15);
    const int rowD = r0 + ((lane >> 4) << 2);
    const int rA   = r0 + (lane & 15);
    const int kfo  = (lane >> 4) << 3;
    const float bias0 = isA ? (bih0[colD] + bhh0[colD]) : (bih1[colD] + bhh1[colD]);
    const float bias1 = isA ? (bih0[colD + 16] + bhh0[colD + 16])
                            : (bih1[colD + 16] + bhh1[colD + 16]);
    __syncthreads();

    // 3-pass GEMM half: hi@Whi + lo@Whi + hi@Wlo, K=512 window at koff
    auto hhalf_mfma = [&](const __bf16* hi_row, const __bf16* lo_row, int koff,
                          f32x4& a0, f32x4& a1) {
#pragma unroll
        for (int kk = 0; kk < 16; ++kk) {
            bf16x8 hh = *reinterpret_cast<const bf16x8*>(hi_row + kk * 32 + kfo);
            bf16x8 w0h = *reinterpret_cast<const bf16x8*>(&WH[(((koff + kk) * 2 + 0) * 64 + lane) * 8]);
            bf16x8 w1h = *reinterpret_cast<const bf16x8*>(&WH[(((koff + kk) * 2 + 1) * 64 + lane) * 8]);
            bf16x8 w0l = *reinterpret_cast<const bf16x8*>(&WL[(((koff + kk) * 2 + 0) * 64 + lane) * 8]);
            bf16x8 w1l = *reinterpret_cast<const bf16x8*>(&WL[(((koff + kk) * 2 + 1) * 64 + lane) * 8]);
            a0 = __builtin_amdgcn_mfma_f32_16x16x32_bf16(hh, w0h, a0, 0, 0, 0);
            a1 = __builtin_amdgcn_mfma_f32_16x16x32_bf16(hh, w1h, a1, 0, 0, 0);
            a0 = __builtin_amdgcn_mfma_f32_16x16x32_bf16(hh, w0l, a0, 0, 0, 0);
            a1 = __builtin_amdgcn_mfma_f32_16x16x32_bf16(hh, w1l, a1, 0, 0, 0);
        }
#pragma unroll
        for (int kk = 0; kk < 16; ++kk) {
            bf16x8 hl = *reinterpret_cast<const bf16x8*>(lo_row + kk * 32 + kfo);
            bf16x8 w0h = *reinterpret_cast<const bf16x8*>(&WH[(((koff + kk) * 2 + 0) * 64 + lane) * 8]);
            bf16x8 w1h = *reinterpret_cast<const bf16x8*>(&WH[(((koff + kk) * 2 + 1) * 64 + lane) * 8]);
            a0 = __builtin_amdgcn_mfma_f32_16x16x32_bf16(hl, w0h, a0, 0, 0, 0);
            a1 = __builtin_amdgcn_mfma_f32_16x16x32_bf16(hl, w1h, a1, 0, 0, 0);
        }
    };

    // A: prefetch preact(0) fragments (d_out currently holds preact everywhere)
    f32x4 pa0, pa1;
    if (isA) {
#pragma unroll
        for (int m = 0; m < 4; ++m) {
            pa0[m] = __builtin_nontemporal_load(
                &out[((size_t)(rowD + m) * TDIM + 0) * HDIM + colD]);
            pa1[m] = __builtin_nontemporal_load(
                &out[((size_t)(rowD + m) * TDIM + 0) * HDIM + colD + 16]);
        }
    }

    float vout[2][4];

    for (int k = 0; k <= TDIM; ++k) {
        // ================= critical compute =================
        if (isA && k < TDIM) {
            const __bf16* hs = h0base + ((k + 3) & 3) * (2 * BH);   // h0(k-1)
            f32x4 acc0 = pa0, acc1 = pa1;
            hhalf_mfma(hs + rA * HDIM, hs + BH + rA * HDIM, 0, acc0, acc1);
            __bf16* hd = h0base + (k & 3) * (2 * BH);               // h0(k)
#pragma unroll
            for (int m = 0; m < 4; ++m) {
                float v0 = fast_tanh(acc0[m] + bias0);
                float v1 = fast_tanh(acc1[m] + bias1);
                __bf16 a = (__bf16)v0, b = (__bf16)v1;
                hd[(rowD + m) * HDIM + colD] = a;
                hd[(rowD + m) * HDIM + colD + 16] = b;
                hd[BH + (rowD + m) * HDIM + colD] = (__bf16)(v0 - (float)a);
                hd[BH + (rowD + m) * HDIM + colD + 16] = (__bf16)(v1 - (float)b);
                if (k == TDIM - 1) {   // final_h layer 0
                    out[(size_t)BDIM * TDIM * HDIM + (size_t)(rowD + m) * HDIM + colD] = v0;
                    out[(size_t)BDIM * TDIM * HDIM + (size_t)(rowD + m) * HDIM + colD + 16] = v1;
                }
            }
        } else if (!isA && k >= 1) {
            const __bf16* s0 = h0base + ((k + 3) & 3) * (2 * BH);   // h0(k-1)
            const __bf16* s1 = h1base + (k & 1) * (2 * BH);         // h1(k-2)
            f32x4 acc0 = {0.f, 0.f, 0.f, 0.f}, acc1 = {0.f, 0.f, 0.f, 0.f};
            hhalf_mfma(s1 + rA * HDIM, s1 + BH + rA * HDIM, 16, acc0, acc1);  // @Whh1
            hhalf_mfma(s0 + rA * HDIM, s0 + BH + rA * HDIM, 0, acc0, acc1);   // @Wih1
            __bf16* hd = h1base + ((k + 1) & 1) * (2 * BH);         // h1(k-1)
#pragma unroll
            for (int m = 0; m < 4; ++m) {
                vout[0][m] = fast_tanh(acc0[m] + bias0);
                vout[1][m] = fast_tanh(acc1[m] + bias1);
                if (k < TDIM) {
                    __bf16 a = (__bf16)vout[0][m], b = (__bf16)vout[1][m];
                    hd[(rowD + m) * HDIM + colD] = a;
                    hd[(rowD + m) * HDIM + colD + 16] = b;
                    hd[BH + (rowD + m) * HDIM + colD] = (__bf16)(vout[0][m] - (float)a);
                    hd[BH + (rowD + m) * HDIM + colD + 16] = (__bf16)(vout[1][m] - (float)b);
                }
            }
            if (k == TDIM) {  // last iter: no barrier follows — store outputs inline
                const int t = k - 1;
#pragma unroll
                for (int m = 0; m < 4; ++m) {
                    __builtin_nontemporal_store(vout[0][m],
                        &out[((size_t)(rowD + m) * TDIM + t) * HDIM + colD]);
                    __builtin_nontemporal_store(vout[1][m],
                        &out[((size_t)(rowD + m) * TDIM + t) * HDIM + colD + 16]);
                    out[(size_t)BDIM * TDIM * HDIM + (size_t)(BDIM + rowD + m) * HDIM + colD] = vout[0][m];
                    out[(size_t)BDIM * TDIM * HDIM + (size_t)(BDIM + rowD + m) * HDIM + colD + 16] = vout[1][m];
                }
            }
        }

        // ================= arrive: release store publishes h =================
        if (k < TDIM) {
            __syncthreads();   // all block stores drained to L2 (vmcnt 0)
            if (tx == 0)
                __hip_atomic_store(&flags[blk * 32], (unsigned)(k + 1),
                                   __ATOMIC_RELEASE, __HIP_MEMORY_SCOPE_AGENT);
        }

        // ======== barrier window: off-critical-path work ========
        if (isA) {
            if (k + 1 < TDIM) {   // prefetch preact(k+1); B can't overwrite it yet
#pragma unroll
                for (int m = 0; m < 4; ++m) {
                    pa0[m] = __builtin_nontemporal_load(
                        &out[((size_t)(rowD + m) * TDIM + (k + 1)) * HDIM + colD]);
                    pa1[m] = __builtin_nontemporal_load(
                        &out[((size_t)(rowD + m) * TDIM + (k + 1)) * HDIM + colD + 16]);
                }
            }
        } else if (k >= 1 && k < TDIM) {
            const int t = k - 1;   // streaming output[b, t, :] (overwrites consumed preact)
#pragma unroll
            for (int m = 0; m < 4; ++m) {
                __builtin_nontemporal_store(vout[0][m],
                    &out[((size_t)(rowD + m) * TDIM + t) * HDIM + colD]);
                __builtin_nontemporal_store(vout[1][m],
                    &out[((size_t)(rowD + m) * TDIM + t) * HDIM + colD + 16]);
            }
        }

        // ================= wait: relaxed spin + one acquire fence =================
        if (k < TDIM) {
            if (wv == 0) {
                const int fl = lane & 31;
                unsigned tgt = (unsigned)(k + 1);
                if (isA && fl >= NA) tgt = (k >= 2) ? (unsigned)(k - 2) : 0u;  // 4-slot WAR slack
                int spins = 0;
                while (true) {
                    unsigned f = __hip_atomic_load(&flags[fl * 32], __ATOMIC_RELAXED,
                                                   __HIP_MEMORY_SCOPE_AGENT);
                    if (__all((int)(f >= tgt))) break;
                    if ((++spins & 127) == 0)   // progress fallback if relaxed load caches
                        __builtin_amdgcn_fence(__ATOMIC_ACQUIRE, "agent");
                    __builtin_amdgcn_s_sleep(1);
                }
                __builtin_amdgcn_fence(__ATOMIC_ACQUIRE, "agent");  // invalidate L1/L2 once
            }
            __syncthreads();
        }
    }
}

extern "C" void kernel_launch(void* const* d_in, const int* in_sizes, int n_in,
                              void* d_out, int out_size, void* d_ws, size_t ws_size,
                              hipStream_t stream) {
    (void)in_sizes; (void)n_in; (void)out_size; (void)ws_size;
    const float* x    = (const float*)d_in[0];
    const float* wih0 = (const float*)d_in[1];
    const float* whh0 = (const float*)d_in[2];
    const float* bih0 = (const float*)d_in[3];
    const float* bhh0 = (const float*)d_in[4];
    const float* wih1 = (const float*)d_in[5];
    const float* whh1 = (const float*)d_in[6];
    const float* bih1 = (const float*)d_in[7];
    const float* bhh1 = (const float*)d_in[8];
    float* out = (float*)d_out;
    unsigned char* ws = (unsigned char*)d_ws;

    // zero flags (32 x 128B) + h0 ring (4 slots) + h1 ring (2 slots)
    hipMemsetAsync(ws, 0, 4096 + 6 * (size_t)(2 * BDIM * HDIM * 2), stream);

    // Phase 1: preact0 -> d_out (all timesteps, fully parallel)
    xw0_gemm<<<dim3(8192), dim3(256), 0, stream>>>(x, wih0, out);

    // Phase 2: persistent recurrence
    void* args[] = {&whh0, &bih0, &bhh0, &wih1, &whh1, &bih1, &bhh1, &out, &ws};
    hipError_t err = hipLaunchCooperativeKernel((void*)rnn_persistent, dim3(NBLK),
                                                dim3(256), args, 0, stream);
    if (err != hipSuccess) {
        rnn_persistent<<<dim3(NBLK), dim3(256), 0, stream>>>(
            whh0, bih0, bhh0, wih1, whh1, bih1, bhh1, out, ws);
    }
}